// Round 1
// baseline (4996.827 us; speedup 1.0000x reference)
//
#include <hip/hip_runtime.h>
#include <math.h>

// ---- problem constants ----
#define BATCH   2
#define SEQLEN  1024
#define DMODEL  1024
#define DINNER  2048
#define VOCABSZ 32000
#define DSTATE  16
#define DCONVK  4
#define DTRANK  64
#define NLAYERS 2
#define MROWS   (BATCH*SEQLEN)   // 2048 token rows
#define EPSF    1e-5f

// ---- helpers ----
__device__ __forceinline__ float siluf(float x){ return x / (1.f + expf(-x)); }
__device__ __forceinline__ float softplusf(float x){
    // stable log1p(exp(x)) == max(x,0) + log1p(exp(-|x|))  (matches jax.nn.softplus)
    return fmaxf(x, 0.f) + log1pf(expf(-fabsf(x)));
}

// ---- embedding gather: x[m,:] = embed[tok[m],:] ----
__global__ __launch_bounds__(256)
void embed_kernel(const int* __restrict__ tok, const float* __restrict__ embed,
                  float* __restrict__ x)
{
    int m = blockIdx.x;
    int t = tok[m];
    const float4* src = (const float4*)(embed + (size_t)t * DMODEL);
    float4* dst = (float4*)(x + (size_t)m * DMODEL);
    dst[threadIdx.x] = src[threadIdx.x];   // 256 * float4 = 1024 floats
}

// ---- rmsnorm: out[m,:] = x[m,:] * rsqrt(mean(x^2)+eps) * w ----
__global__ __launch_bounds__(256)
void rmsnorm_kernel(const float* __restrict__ x, const float* __restrict__ w,
                    float* __restrict__ out)
{
    int m = blockIdx.x;
    const float4* xr = (const float4*)(x + (size_t)m * DMODEL);
    float4 v = xr[threadIdx.x];
    float ss = v.x*v.x + v.y*v.y + v.z*v.z + v.w*v.w;
    #pragma unroll
    for (int o = 1; o < 64; o <<= 1) ss += __shfl_xor(ss, o, 64);
    __shared__ float partial[4];
    if ((threadIdx.x & 63) == 0) partial[threadIdx.x >> 6] = ss;
    __syncthreads();
    float tot = partial[0] + partial[1] + partial[2] + partial[3];
    float rs = rsqrtf(tot / (float)DMODEL + EPSF);
    float4 wv = ((const float4*)w)[threadIdx.x];
    float4 o;
    o.x = v.x * rs * wv.x; o.y = v.y * rs * wv.y;
    o.z = v.z * rs * wv.z; o.w = v.w * rs * wv.w;
    ((float4*)(out + (size_t)m * DMODEL))[threadIdx.x] = o;
}

// ---- fp32 GEMM: C[M,N] = A[M,K] * W[N,K]^T  (weights row-major [out,in]) ----
// BM=128 BN=64 BK=16, 256 threads, 8x4 per-thread tile.
#define BM 128
#define BN 64
#define BK 16
enum { EP_NONE = 0, EP_SOFTPLUS = 1, EP_RESID = 2 };

template<int EP>
__global__ __launch_bounds__(256)
void gemm_bt(const float* __restrict__ A, int lda,
             const float* __restrict__ W,
             float* __restrict__ C, int ldc,
             const float* __restrict__ bias,
             int M, int N, int K)
{
    __shared__ float As[BK][BM + 4];  // +4 pad: float4-aligned rows, 2-way write conflicts only
    __shared__ float Ws[BK][BN + 4];

    const int tid  = threadIdx.x;
    const int row0 = blockIdx.y * BM;
    const int col0 = blockIdx.x * BN;

    // staging maps: contiguous-in-K loads (coalesced 64B bursts per row)
    const int ar  = tid >> 2;    // 0..63 (A rows, 2 iters for 128)
    const int akq = tid & 3;     // which float4 of the BK=16 slice
    const int wr  = tid >> 2;    // 0..63 (W rows)
    const int wkq = tid & 3;

    const int ty = tid >> 4, tx = tid & 15;  // 16x16 compute grid
    float acc[8][4];
    #pragma unroll
    for (int i = 0; i < 8; i++)
        #pragma unroll
        for (int j = 0; j < 4; j++) acc[i][j] = 0.f;

    const float* Arow0 = A + (size_t)(row0 + ar) * lda;
    const float* Arow1 = A + (size_t)(row0 + ar + 64) * lda;
    const bool wvalid  = (col0 + wr) < N;
    const float* Wrow  = W + (size_t)(col0 + wr) * K;

    for (int kb = 0; kb < K; kb += BK) {
        {   // A tile -> As[k][m]
            float4 v0 = *(const float4*)(Arow0 + kb + akq * 4);
            float4 v1 = *(const float4*)(Arow1 + kb + akq * 4);
            As[akq*4+0][ar]    = v0.x; As[akq*4+1][ar]    = v0.y;
            As[akq*4+2][ar]    = v0.z; As[akq*4+3][ar]    = v0.w;
            As[akq*4+0][ar+64] = v1.x; As[akq*4+1][ar+64] = v1.y;
            As[akq*4+2][ar+64] = v1.z; As[akq*4+3][ar+64] = v1.w;
        }
        {   // W tile -> Ws[k][n]
            float4 v = wvalid ? *(const float4*)(Wrow + kb + wkq * 4)
                              : make_float4(0.f, 0.f, 0.f, 0.f);
            Ws[wkq*4+0][wr] = v.x; Ws[wkq*4+1][wr] = v.y;
            Ws[wkq*4+2][wr] = v.z; Ws[wkq*4+3][wr] = v.w;
        }
        __syncthreads();
        #pragma unroll
        for (int kk = 0; kk < BK; kk++) {
            float4 a0 = *(const float4*)&As[kk][ty * 8];
            float4 a1 = *(const float4*)&As[kk][ty * 8 + 4];
            float4 b  = *(const float4*)&Ws[kk][tx * 4];
            float av[8] = {a0.x,a0.y,a0.z,a0.w,a1.x,a1.y,a1.z,a1.w};
            float bv[4] = {b.x,b.y,b.z,b.w};
            #pragma unroll
            for (int i = 0; i < 8; i++)
                #pragma unroll
                for (int j = 0; j < 4; j++)
                    acc[i][j] = fmaf(av[i], bv[j], acc[i][j]);
        }
        __syncthreads();
    }

    // epilogue
    const int col = col0 + tx * 4;
    #pragma unroll
    for (int i = 0; i < 8; i++) {
        int row = row0 + ty * 8 + i;
        float* crow = C + (size_t)row * ldc;
        if (col + 4 <= N) {
            float4 o;
            if (EP == EP_SOFTPLUS) {
                float4 bv = *(const float4*)(bias + col);
                o.x = softplusf(acc[i][0] + bv.x);
                o.y = softplusf(acc[i][1] + bv.y);
                o.z = softplusf(acc[i][2] + bv.z);
                o.w = softplusf(acc[i][3] + bv.w);
            } else if (EP == EP_RESID) {
                float4 p = *(const float4*)(crow + col);
                o.x = p.x + acc[i][0]; o.y = p.y + acc[i][1];
                o.z = p.z + acc[i][2]; o.w = p.w + acc[i][3];
            } else {
                o.x = acc[i][0]; o.y = acc[i][1]; o.z = acc[i][2]; o.w = acc[i][3];
            }
            *(float4*)(crow + col) = o;
        } else {
            #pragma unroll
            for (int j = 0; j < 4; j++) {
                int c = col + j;
                if (c < N) {
                    float v = acc[i][j];
                    if (EP == EP_SOFTPLUS) v = softplusf(v + bias[c]);
                    else if (EP == EP_RESID) v += crow[c];
                    crow[c] = v;
                }
            }
        }
    }
}

// ---- causal depthwise conv(4) + bias + silu, and conv-cache extraction ----
__global__ __launch_bounds__(256)
void conv_silu_kernel(const float* __restrict__ xz, const float* __restrict__ cw,
                      const float* __restrict__ cb, float* __restrict__ xs,
                      float* __restrict__ cacheOut)
{
    int idx = blockIdx.x * 256 + threadIdx.x;        // over MROWS*DINNER
    int m = idx >> 11;          // token row (b*L + l)
    int d = idx & (DINNER - 1);
    int l = m & (SEQLEN - 1);
    float4 w4 = *(const float4*)(cw + d * 4);
    float x0 = (l >= 3) ? xz[(size_t)(m - 3) * (2*DINNER) + d] : 0.f;
    float x1 = (l >= 2) ? xz[(size_t)(m - 2) * (2*DINNER) + d] : 0.f;
    float x2 = (l >= 1) ? xz[(size_t)(m - 1) * (2*DINNER) + d] : 0.f;
    float x3 =            xz[(size_t)m       * (2*DINNER) + d];
    float acc = cb[d] + x0*w4.x + x1*w4.y + x2*w4.z + x3*w4.w;
    xs[(size_t)m * DINNER + d] = siluf(acc);
    if (l >= SEQLEN - 3) {   // cache = xi[:, L-3:, :] (transposed layout (B,DI,3))
        int j = l - (SEQLEN - 3);
        int b = m >> 10;
        cacheOut[((size_t)b * DINNER + d) * 3 + j] = x3;
    }
}

// ---- selective scan: thread per (b,d,n); 16-lane shfl reduce for y; gating fused ----
__global__ __launch_bounds__(256)
void scan_kernel(const float* __restrict__ delta, const float* __restrict__ dbl,
                 const float* __restrict__ xs, const float* __restrict__ xz,
                 const float* __restrict__ A_log, const float* __restrict__ Dp,
                 float* __restrict__ y, float* __restrict__ hs_out)
{
    const int tid = threadIdx.x;
    const int ch = tid >> 4, n = tid & 15;
    const int g = blockIdx.x * 16 + ch;       // 0 .. B*DINNER-1
    const int b = g >> 11, d = g & (DINNER - 1);
    const float a  = -expf(A_log[(size_t)d * DSTATE + n]);
    const float dp = Dp[d];
    float h = 0.f;
    const size_t mbase = (size_t)b * SEQLEN;
    for (int t = 0; t < SEQLEN; t++) {
        size_t m = mbase + t;
        float dl = delta[m * DINNER + d];
        float xv = xs[m * DINNER + d];
        float Bn = dbl[m * 96 + 64 + n];
        float Cn = dbl[m * 96 + 80 + n];
        float dA = expf(dl * a);
        h = fmaf(dA, h, dl * Bn * xv);
        float p = h * Cn;
        p += __shfl_xor(p, 1, 64); p += __shfl_xor(p, 2, 64);
        p += __shfl_xor(p, 4, 64); p += __shfl_xor(p, 8, 64);
        if (n == 0) {
            float z = xz[m * (2*DINNER) + DINNER + d];
            float yv = p + dp * xv;
            y[m * DINNER + d] = yv * siluf(z);
        }
    }
    hs_out[((size_t)b * DINNER + d) * DSTATE + n] = h;
}

// ---- driver ----
extern "C" void kernel_launch(void* const* d_in, const int* in_sizes, int n_in,
                              void* d_out, int out_size, void* d_ws, size_t ws_size,
                              hipStream_t stream)
{
    const int*   tokens     = (const int*)  d_in[0];
    const float* embed      = (const float*)d_in[1];
    const float* in_proj_w  = (const float*)d_in[2];
    const float* conv_w     = (const float*)d_in[3];
    const float* conv_b     = (const float*)d_in[4];
    const float* x_proj_w   = (const float*)d_in[5];
    const float* dt_proj_w  = (const float*)d_in[6];
    const float* dt_proj_b  = (const float*)d_in[7];
    const float* A_log      = (const float*)d_in[8];
    const float* D_param    = (const float*)d_in[9];
    const float* out_proj_w = (const float*)d_in[10];
    const float* rms_w      = (const float*)d_in[11];
    const float* norm_f_w   = (const float*)d_in[12];

    float* outp   = (float*)d_out;
    float* logits = outp;                                           // (B,L,VOCAB)
    float* hs     = outp + (size_t)MROWS * VOCABSZ;                 // (NL,B,DI,16)
    float* caches = hs + (size_t)NLAYERS * BATCH * DINNER * DSTATE; // (NL,B,DI,3)

    float* ws    = (float*)d_ws;
    float* x     = ws;                                    // MROWS*DMODEL
    float* xn    = x     + (size_t)MROWS * DMODEL;        // MROWS*DMODEL
    float* xz    = xn    + (size_t)MROWS * DMODEL;        // MROWS*2*DINNER
    float* xs    = xz    + (size_t)MROWS * 2 * DINNER;    // MROWS*DINNER
    float* dbl   = xs    + (size_t)MROWS * DINNER;        // MROWS*96
    float* delta = dbl   + (size_t)MROWS * 96;            // MROWS*DINNER
    float* yb    = delta + (size_t)MROWS * DINNER;        // MROWS*DINNER
    // total ~101.5 MB of d_ws

    embed_kernel<<<MROWS, 256, 0, stream>>>(tokens, embed, x);

    for (int l = 0; l < NLAYERS; l++) {
        rmsnorm_kernel<<<MROWS, 256, 0, stream>>>(x, rms_w + (size_t)l * DMODEL, xn);

        gemm_bt<EP_NONE><<<dim3(2*DINNER/BN, MROWS/BM), 256, 0, stream>>>(
            xn, DMODEL, in_proj_w + (size_t)l * 2*DINNER*DMODEL,
            xz, 2*DINNER, nullptr, MROWS, 2*DINNER, DMODEL);

        conv_silu_kernel<<<(MROWS*DINNER)/256, 256, 0, stream>>>(
            xz, conv_w + (size_t)l * DINNER * DCONVK, conv_b + (size_t)l * DINNER,
            xs, caches + (size_t)l * BATCH * DINNER * 3);

        gemm_bt<EP_NONE><<<dim3((96 + BN - 1)/BN, MROWS/BM), 256, 0, stream>>>(
            xs, DINNER, x_proj_w + (size_t)l * 96 * DINNER,
            dbl, 96, nullptr, MROWS, 96, DINNER);

        gemm_bt<EP_SOFTPLUS><<<dim3(DINNER/BN, MROWS/BM), 256, 0, stream>>>(
            dbl, 96, dt_proj_w + (size_t)l * DINNER * DTRANK,
            delta, DINNER, dt_proj_b + (size_t)l * DINNER, MROWS, DINNER, DTRANK);

        scan_kernel<<<(BATCH*DINNER)/16, 256, 0, stream>>>(
            delta, dbl, xs, xz,
            A_log + (size_t)l * DINNER * DSTATE, D_param + (size_t)l * DINNER,
            yb, hs + (size_t)l * BATCH * DINNER * DSTATE);

        gemm_bt<EP_RESID><<<dim3(DMODEL/BN, MROWS/BM), 256, 0, stream>>>(
            yb, DINNER, out_proj_w + (size_t)l * DMODEL * DINNER,
            x, DMODEL, nullptr, MROWS, DMODEL, DINNER);
    }

    rmsnorm_kernel<<<MROWS, 256, 0, stream>>>(x, norm_f_w, xn);

    gemm_bt<EP_NONE><<<dim3(VOCABSZ/BN, MROWS/BM), 256, 0, stream>>>(
        xn, DMODEL, embed, logits, VOCABSZ, nullptr, MROWS, VOCABSZ, DMODEL);
}

// Round 2
// 3481.871 us; speedup vs baseline: 1.4351x; 1.4351x over previous
//
#include <hip/hip_runtime.h>
#include <math.h>

// ---- problem constants ----
#define BATCH   2
#define SEQLEN  1024
#define DMODEL  1024
#define DINNER  2048
#define VOCABSZ 32000
#define DSTATE  16
#define DCONVK  4
#define DTRANK  64
#define NLAYERS 2
#define MROWS   (BATCH*SEQLEN)   // 2048 token rows
#define EPSF    1e-5f

// ---- helpers ----
__device__ __forceinline__ float siluf(float x){ return x / (1.f + expf(-x)); }
__device__ __forceinline__ float softplusf(float x){
    return fmaxf(x, 0.f) + log1pf(expf(-fabsf(x)));
}
__device__ __forceinline__ unsigned short f2bf(float f){
    unsigned int u = __float_as_uint(f);
    unsigned int r = (u + 0x7FFFu + ((u >> 16) & 1u)) >> 16;   // RNE
    return (unsigned short)r;
}

// ---- embedding gather ----
__global__ __launch_bounds__(256)
void embed_kernel(const int* __restrict__ tok, const float* __restrict__ embed,
                  float* __restrict__ x)
{
    int m = blockIdx.x;
    int t = tok[m];
    const float4* src = (const float4*)(embed + (size_t)t * DMODEL);
    float4* dst = (float4*)(x + (size_t)m * DMODEL);
    dst[threadIdx.x] = src[threadIdx.x];
}

// ---- rmsnorm ----
__global__ __launch_bounds__(256)
void rmsnorm_kernel(const float* __restrict__ x, const float* __restrict__ w,
                    float* __restrict__ out)
{
    int m = blockIdx.x;
    const float4* xr = (const float4*)(x + (size_t)m * DMODEL);
    float4 v = xr[threadIdx.x];
    float ss = v.x*v.x + v.y*v.y + v.z*v.z + v.w*v.w;
    #pragma unroll
    for (int o = 1; o < 64; o <<= 1) ss += __shfl_xor(ss, o, 64);
    __shared__ float partial[4];
    if ((threadIdx.x & 63) == 0) partial[threadIdx.x >> 6] = ss;
    __syncthreads();
    float tot = partial[0] + partial[1] + partial[2] + partial[3];
    float rs = rsqrtf(tot / (float)DMODEL + EPSF);
    float4 wv = ((const float4*)w)[threadIdx.x];
    float4 o;
    o.x = v.x * rs * wv.x; o.y = v.y * rs * wv.y;
    o.z = v.z * rs * wv.z; o.w = v.w * rs * wv.w;
    ((float4*)(out + (size_t)m * DMODEL))[threadIdx.x] = o;
}

// ---- fp32 -> bf16 conversion (RNE), vectorized ----
__global__ __launch_bounds__(256)
void f32_to_bf16_kernel(const float* __restrict__ in, unsigned short* __restrict__ out, int n4)
{
    int i = blockIdx.x * 256 + threadIdx.x;
    if (i < n4) {
        float4 v = ((const float4*)in)[i];
        ushort4 o;
        o.x = f2bf(v.x); o.y = f2bf(v.y); o.z = f2bf(v.z); o.w = f2bf(v.w);
        ((ushort4*)out)[i] = o;
    }
}

// ---- fp32 GEMM: C[M,N] = A[M,K] * W[N,K]^T (used for layer projections) ----
#define BM 128
#define BN 64
#define BK 16
enum { EP_NONE = 0, EP_SOFTPLUS = 1, EP_RESID = 2 };

template<int EP>
__global__ __launch_bounds__(256)
void gemm_bt(const float* __restrict__ A, int lda,
             const float* __restrict__ W,
             float* __restrict__ C, int ldc,
             const float* __restrict__ bias,
             int M, int N, int K)
{
    __shared__ float As[BK][BM + 4];
    __shared__ float Ws[BK][BN + 4];

    const int tid  = threadIdx.x;
    const int row0 = blockIdx.y * BM;
    const int col0 = blockIdx.x * BN;

    const int ar  = tid >> 2;
    const int akq = tid & 3;
    const int wr  = tid >> 2;
    const int wkq = tid & 3;

    const int ty = tid >> 4, tx = tid & 15;
    float acc[8][4];
    #pragma unroll
    for (int i = 0; i < 8; i++)
        #pragma unroll
        for (int j = 0; j < 4; j++) acc[i][j] = 0.f;

    const float* Arow0 = A + (size_t)(row0 + ar) * lda;
    const float* Arow1 = A + (size_t)(row0 + ar + 64) * lda;
    const bool wvalid  = (col0 + wr) < N;
    const float* Wrow  = W + (size_t)(col0 + wr) * K;

    for (int kb = 0; kb < K; kb += BK) {
        {
            float4 v0 = *(const float4*)(Arow0 + kb + akq * 4);
            float4 v1 = *(const float4*)(Arow1 + kb + akq * 4);
            As[akq*4+0][ar]    = v0.x; As[akq*4+1][ar]    = v0.y;
            As[akq*4+2][ar]    = v0.z; As[akq*4+3][ar]    = v0.w;
            As[akq*4+0][ar+64] = v1.x; As[akq*4+1][ar+64] = v1.y;
            As[akq*4+2][ar+64] = v1.z; As[akq*4+3][ar+64] = v1.w;
        }
        {
            float4 v = wvalid ? *(const float4*)(Wrow + kb + wkq * 4)
                              : make_float4(0.f, 0.f, 0.f, 0.f);
            Ws[wkq*4+0][wr] = v.x; Ws[wkq*4+1][wr] = v.y;
            Ws[wkq*4+2][wr] = v.z; Ws[wkq*4+3][wr] = v.w;
        }
        __syncthreads();
        #pragma unroll
        for (int kk = 0; kk < BK; kk++) {
            float4 a0 = *(const float4*)&As[kk][ty * 8];
            float4 a1 = *(const float4*)&As[kk][ty * 8 + 4];
            float4 b  = *(const float4*)&Ws[kk][tx * 4];
            float av[8] = {a0.x,a0.y,a0.z,a0.w,a1.x,a1.y,a1.z,a1.w};
            float bv[4] = {b.x,b.y,b.z,b.w};
            #pragma unroll
            for (int i = 0; i < 8; i++)
                #pragma unroll
                for (int j = 0; j < 4; j++)
                    acc[i][j] = fmaf(av[i], bv[j], acc[i][j]);
        }
        __syncthreads();
    }

    const int col = col0 + tx * 4;
    #pragma unroll
    for (int i = 0; i < 8; i++) {
        int row = row0 + ty * 8 + i;
        float* crow = C + (size_t)row * ldc;
        if (col + 4 <= N) {
            float4 o;
            if (EP == EP_SOFTPLUS) {
                float4 bv = *(const float4*)(bias + col);
                o.x = softplusf(acc[i][0] + bv.x);
                o.y = softplusf(acc[i][1] + bv.y);
                o.z = softplusf(acc[i][2] + bv.z);
                o.w = softplusf(acc[i][3] + bv.w);
            } else if (EP == EP_RESID) {
                float4 p = *(const float4*)(crow + col);
                o.x = p.x + acc[i][0]; o.y = p.y + acc[i][1];
                o.z = p.z + acc[i][2]; o.w = p.w + acc[i][3];
            } else {
                o.x = acc[i][0]; o.y = acc[i][1]; o.z = acc[i][2]; o.w = acc[i][3];
            }
            *(float4*)(crow + col) = o;
        } else {
            #pragma unroll
            for (int j = 0; j < 4; j++) {
                int c = col + j;
                if (c < N) {
                    float v = acc[i][j];
                    if (EP == EP_SOFTPLUS) v = softplusf(v + bias[c]);
                    else if (EP == EP_RESID) v += crow[c];
                    crow[c] = v;
                }
            }
        }
    }
}

// ---- bf16 MFMA GEMM: C[M,N] = A[M,K] * B[N,K]^T, fp32 out (m97-structure) ----
// 128x128 tile, BK=32, 4 waves each owning a 64x64 quadrant (4x4 fragments of
// 16x16x32 MFMA). Staging via global_load_lds width=16, linear LDS layout.
typedef __attribute__((ext_vector_type(8))) short bf16x8;
typedef __attribute__((ext_vector_type(4))) float f32x4;

#define GBM 128
#define GBN 128
#define GBK 32

__global__ __launch_bounds__(256)
void gemm_mfma_bf16(const unsigned short* __restrict__ A,   // [M][K] bf16
                    const unsigned short* __restrict__ B,   // [N][K] bf16
                    float* __restrict__ C, int M, int N, int K)
{
    __shared__ __align__(16) unsigned short As[GBM * GBK];  // 8 KB
    __shared__ __align__(16) unsigned short Bs[GBN * GBK];  // 8 KB

    const int tid  = threadIdx.x;
    const int wave = tid >> 6, lane = tid & 63;
    const int row0 = blockIdx.y * GBM, col0 = blockIdx.x * GBN;
    const int wr = wave >> 1, wc = wave & 1;

    f32x4 acc[4][4] = {};

    // staging map: wave w instr j covers tile rows (w*2+j)*16 .. +15;
    // lane l -> row +(l>>2), k-offset (l&3)*8 elems (16B). LDS fills linearly
    // at lane*16B which matches row-major [128][32] exactly (no per-lane scatter).
    const int srow  = lane >> 2;
    const int skoff = (lane & 3) * 8;

    for (int kb = 0; kb < K; kb += GBK) {
        __syncthreads();   // previous iteration's LDS reads done
        #pragma unroll
        for (int j = 0; j < 2; j++) {
            const int s = wave * 2 + j;
            const unsigned short* ga = A + (size_t)(row0 + s*16 + srow) * K + kb + skoff;
            __builtin_amdgcn_global_load_lds(
                (const __attribute__((address_space(1))) void*)ga,
                (__attribute__((address_space(3))) void*)(As + s * 512), 16, 0, 0);
            const unsigned short* gb = B + (size_t)(col0 + s*16 + srow) * K + kb + skoff;
            __builtin_amdgcn_global_load_lds(
                (const __attribute__((address_space(1))) void*)gb,
                (__attribute__((address_space(3))) void*)(Bs + s * 512), 16, 0, 0);
        }
        __syncthreads();   // staging complete (compiler drains vmcnt before barrier)

        const int fr = lane & 15, q = (lane >> 4) * 8;
        bf16x8 af[4], bfr[4];
        #pragma unroll
        for (int m = 0; m < 4; m++)
            af[m] = *(const bf16x8*)&As[(wr*64 + m*16 + fr) * GBK + q];
        #pragma unroll
        for (int n = 0; n < 4; n++)
            bfr[n] = *(const bf16x8*)&Bs[(wc*64 + n*16 + fr) * GBK + q];
        #pragma unroll
        for (int m = 0; m < 4; m++)
            #pragma unroll
            for (int n = 0; n < 4; n++)
                acc[m][n] = __builtin_amdgcn_mfma_f32_16x16x32_bf16(af[m], bfr[n], acc[m][n], 0, 0, 0);
    }

    // epilogue: C/D layout col=lane&15, row=(lane>>4)*4+reg (guide §3, m89/m91)
    const int fr = lane & 15, rq = lane >> 4;
    #pragma unroll
    for (int m = 0; m < 4; m++) {
        #pragma unroll
        for (int j = 0; j < 4; j++) {
            int row = row0 + wr*64 + m*16 + rq*4 + j;
            float* crow = C + (size_t)row * N;
            #pragma unroll
            for (int n = 0; n < 4; n++)
                crow[col0 + wc*64 + n*16 + fr] = acc[m][n][j];
        }
    }
}

// ---- causal depthwise conv(4) + bias + silu + cache extraction ----
__global__ __launch_bounds__(256)
void conv_silu_kernel(const float* __restrict__ xz, const float* __restrict__ cw,
                      const float* __restrict__ cb, float* __restrict__ xs,
                      float* __restrict__ cacheOut)
{
    int idx = blockIdx.x * 256 + threadIdx.x;
    int m = idx >> 11;
    int d = idx & (DINNER - 1);
    int l = m & (SEQLEN - 1);
    float4 w4 = *(const float4*)(cw + d * 4);
    float x0 = (l >= 3) ? xz[(size_t)(m - 3) * (2*DINNER) + d] : 0.f;
    float x1 = (l >= 2) ? xz[(size_t)(m - 2) * (2*DINNER) + d] : 0.f;
    float x2 = (l >= 1) ? xz[(size_t)(m - 1) * (2*DINNER) + d] : 0.f;
    float x3 =            xz[(size_t)m       * (2*DINNER) + d];
    float acc = cb[d] + x0*w4.x + x1*w4.y + x2*w4.z + x3*w4.w;
    xs[(size_t)m * DINNER + d] = siluf(acc);
    if (l >= SEQLEN - 3) {
        int j = l - (SEQLEN - 3);
        int b = m >> 10;
        cacheOut[((size_t)b * DINNER + d) * 3 + j] = x3;
    }
}

// ---- selective scan ----
__global__ __launch_bounds__(256)
void scan_kernel(const float* __restrict__ delta, const float* __restrict__ dbl,
                 const float* __restrict__ xs, const float* __restrict__ xz,
                 const float* __restrict__ A_log, const float* __restrict__ Dp,
                 float* __restrict__ y, float* __restrict__ hs_out)
{
    const int tid = threadIdx.x;
    const int ch = tid >> 4, n = tid & 15;
    const int g = blockIdx.x * 16 + ch;
    const int b = g >> 11, d = g & (DINNER - 1);
    const float a  = -expf(A_log[(size_t)d * DSTATE + n]);
    const float dp = Dp[d];
    float h = 0.f;
    const size_t mbase = (size_t)b * SEQLEN;
    for (int t = 0; t < SEQLEN; t++) {
        size_t m = mbase + t;
        float dl = delta[m * DINNER + d];
        float xv = xs[m * DINNER + d];
        float Bn = dbl[m * 96 + 64 + n];
        float Cn = dbl[m * 96 + 80 + n];
        float dA = expf(dl * a);
        h = fmaf(dA, h, dl * Bn * xv);
        float p = h * Cn;
        p += __shfl_xor(p, 1, 64); p += __shfl_xor(p, 2, 64);
        p += __shfl_xor(p, 4, 64); p += __shfl_xor(p, 8, 64);
        if (n == 0) {
            float z = xz[m * (2*DINNER) + DINNER + d];
            float yv = p + dp * xv;
            y[m * DINNER + d] = yv * siluf(z);
        }
    }
    hs_out[((size_t)b * DINNER + d) * DSTATE + n] = h;
}

// ---- driver ----
extern "C" void kernel_launch(void* const* d_in, const int* in_sizes, int n_in,
                              void* d_out, int out_size, void* d_ws, size_t ws_size,
                              hipStream_t stream)
{
    const int*   tokens     = (const int*)  d_in[0];
    const float* embed      = (const float*)d_in[1];
    const float* in_proj_w  = (const float*)d_in[2];
    const float* conv_w     = (const float*)d_in[3];
    const float* conv_b     = (const float*)d_in[4];
    const float* x_proj_w   = (const float*)d_in[5];
    const float* dt_proj_w  = (const float*)d_in[6];
    const float* dt_proj_b  = (const float*)d_in[7];
    const float* A_log      = (const float*)d_in[8];
    const float* D_param    = (const float*)d_in[9];
    const float* out_proj_w = (const float*)d_in[10];
    const float* rms_w      = (const float*)d_in[11];
    const float* norm_f_w   = (const float*)d_in[12];

    float* outp   = (float*)d_out;
    float* logits = outp;
    float* hs     = outp + (size_t)MROWS * VOCABSZ;
    float* caches = hs + (size_t)NLAYERS * BATCH * DINNER * DSTATE;

    float* ws    = (float*)d_ws;
    float* x     = ws;
    float* xn    = x     + (size_t)MROWS * DMODEL;
    float* xz    = xn    + (size_t)MROWS * DMODEL;
    float* xs    = xz    + (size_t)MROWS * 2 * DINNER;
    float* dbl   = xs    + (size_t)MROWS * DINNER;
    float* delta = dbl   + (size_t)MROWS * 96;
    float* yb    = delta + (size_t)MROWS * DINNER;
    unsigned short* xnbf  = (unsigned short*)(yb + (size_t)MROWS * DINNER);  // 4 MB
    unsigned short* embbf = xnbf + (size_t)MROWS * DMODEL;                   // 65.5 MB
    // total ws ~171 MB

    embed_kernel<<<MROWS, 256, 0, stream>>>(tokens, embed, x);

    // bf16 copy of embed (weight for logits GEMM) — per call, ws is re-poisoned
    f32_to_bf16_kernel<<<(VOCABSZ*DMODEL/4 + 255)/256, 256, 0, stream>>>(
        embed, embbf, VOCABSZ*DMODEL/4);

    for (int l = 0; l < NLAYERS; l++) {
        rmsnorm_kernel<<<MROWS, 256, 0, stream>>>(x, rms_w + (size_t)l * DMODEL, xn);

        gemm_bt<EP_NONE><<<dim3(2*DINNER/BN, MROWS/BM), 256, 0, stream>>>(
            xn, DMODEL, in_proj_w + (size_t)l * 2*DINNER*DMODEL,
            xz, 2*DINNER, nullptr, MROWS, 2*DINNER, DMODEL);

        conv_silu_kernel<<<(MROWS*DINNER)/256, 256, 0, stream>>>(
            xz, conv_w + (size_t)l * DINNER * DCONVK, conv_b + (size_t)l * DINNER,
            xs, caches + (size_t)l * BATCH * DINNER * 3);

        gemm_bt<EP_NONE><<<dim3((96 + BN - 1)/BN, MROWS/BM), 256, 0, stream>>>(
            xs, DINNER, x_proj_w + (size_t)l * 96 * DINNER,
            dbl, 96, nullptr, MROWS, 96, DINNER);

        gemm_bt<EP_SOFTPLUS><<<dim3(DINNER/BN, MROWS/BM), 256, 0, stream>>>(
            dbl, 96, dt_proj_w + (size_t)l * DINNER * DTRANK,
            delta, DINNER, dt_proj_b + (size_t)l * DINNER, MROWS, DINNER, DTRANK);

        scan_kernel<<<(BATCH*DINNER)/16, 256, 0, stream>>>(
            delta, dbl, xs, xz,
            A_log + (size_t)l * DINNER * DSTATE, D_param + (size_t)l * DINNER,
            yb, hs + (size_t)l * BATCH * DINNER * DSTATE);

        gemm_bt<EP_RESID><<<dim3(DMODEL/BN, MROWS/BM), 256, 0, stream>>>(
            yb, DINNER, out_proj_w + (size_t)l * DMODEL * DINNER,
            x, DMODEL, nullptr, MROWS, DMODEL, DINNER);
    }

    rmsnorm_kernel<<<MROWS, 256, 0, stream>>>(x, norm_f_w, xn);

    // logits = xn @ embed^T in bf16 MFMA (fp32 accumulate)
    f32_to_bf16_kernel<<<(MROWS*DMODEL/4 + 255)/256, 256, 0, stream>>>(
        xn, xnbf, MROWS*DMODEL/4);

    gemm_mfma_bf16<<<dim3(VOCABSZ/GBN, MROWS/GBM), 256, 0, stream>>>(
        xnbf, embbf, logits, MROWS, VOCABSZ, DMODEL);
}

// Round 3
// 2517.713 us; speedup vs baseline: 1.9847x; 1.3829x over previous
//
#include <hip/hip_runtime.h>
#include <math.h>

// ---- problem constants ----
#define BATCH   2
#define SEQLEN  1024
#define DMODEL  1024
#define DINNER  2048
#define VOCABSZ 32000
#define DSTATE  16
#define DCONVK  4
#define DTRANK  64
#define NLAYERS 2
#define MROWS   (BATCH*SEQLEN)   // 2048 token rows
#define EPSF    1e-5f

// ---- helpers ----
__device__ __forceinline__ float siluf(float x){ return x / (1.f + expf(-x)); }
__device__ __forceinline__ float softplusf(float x){
    return fmaxf(x, 0.f) + log1pf(expf(-fabsf(x)));
}
__device__ __forceinline__ unsigned short f2bf(float f){
    unsigned int u = __float_as_uint(f);
    unsigned int r = (u + 0x7FFFu + ((u >> 16) & 1u)) >> 16;   // RNE
    return (unsigned short)r;
}

// ---- embedding gather ----
__global__ __launch_bounds__(256)
void embed_kernel(const int* __restrict__ tok, const float* __restrict__ embed,
                  float* __restrict__ x)
{
    int m = blockIdx.x;
    int t = tok[m];
    const float4* src = (const float4*)(embed + (size_t)t * DMODEL);
    float4* dst = (float4*)(x + (size_t)m * DMODEL);
    dst[threadIdx.x] = src[threadIdx.x];
}

// ---- rmsnorm ----
__global__ __launch_bounds__(256)
void rmsnorm_kernel(const float* __restrict__ x, const float* __restrict__ w,
                    float* __restrict__ out)
{
    int m = blockIdx.x;
    const float4* xr = (const float4*)(x + (size_t)m * DMODEL);
    float4 v = xr[threadIdx.x];
    float ss = v.x*v.x + v.y*v.y + v.z*v.z + v.w*v.w;
    #pragma unroll
    for (int o = 1; o < 64; o <<= 1) ss += __shfl_xor(ss, o, 64);
    __shared__ float partial[4];
    if ((threadIdx.x & 63) == 0) partial[threadIdx.x >> 6] = ss;
    __syncthreads();
    float tot = partial[0] + partial[1] + partial[2] + partial[3];
    float rs = rsqrtf(tot / (float)DMODEL + EPSF);
    float4 wv = ((const float4*)w)[threadIdx.x];
    float4 o;
    o.x = v.x * rs * wv.x; o.y = v.y * rs * wv.y;
    o.z = v.z * rs * wv.z; o.w = v.w * rs * wv.w;
    ((float4*)(out + (size_t)m * DMODEL))[threadIdx.x] = o;
}

// ---- fp32 -> bf16 conversion (RNE), vectorized ----
__global__ __launch_bounds__(256)
void f32_to_bf16_kernel(const float* __restrict__ in, unsigned short* __restrict__ out, int n4)
{
    int i = blockIdx.x * 256 + threadIdx.x;
    if (i < n4) {
        float4 v = ((const float4*)in)[i];
        ushort4 o;
        o.x = f2bf(v.x); o.y = f2bf(v.y); o.z = f2bf(v.z); o.w = f2bf(v.w);
        ((ushort4*)out)[i] = o;
    }
}

// ---- fp32 GEMM: C[M,N] = A[M,K] * W[N,K]^T (layer projections) ----
#define BM 128
#define BN 64
#define BK 16
enum { EP_NONE = 0, EP_SOFTPLUS = 1, EP_RESID = 2 };

template<int EP>
__global__ __launch_bounds__(256)
void gemm_bt(const float* __restrict__ A, int lda,
             const float* __restrict__ W,
             float* __restrict__ C, int ldc,
             const float* __restrict__ bias,
             int M, int N, int K)
{
    __shared__ float As[BK][BM + 4];
    __shared__ float Ws[BK][BN + 4];

    const int tid  = threadIdx.x;
    const int row0 = blockIdx.y * BM;
    const int col0 = blockIdx.x * BN;

    const int ar  = tid >> 2;
    const int akq = tid & 3;
    const int wr  = tid >> 2;
    const int wkq = tid & 3;

    const int ty = tid >> 4, tx = tid & 15;
    float acc[8][4];
    #pragma unroll
    for (int i = 0; i < 8; i++)
        #pragma unroll
        for (int j = 0; j < 4; j++) acc[i][j] = 0.f;

    const float* Arow0 = A + (size_t)(row0 + ar) * lda;
    const float* Arow1 = A + (size_t)(row0 + ar + 64) * lda;
    const bool wvalid  = (col0 + wr) < N;
    const float* Wrow  = W + (size_t)(col0 + wr) * K;

    for (int kb = 0; kb < K; kb += BK) {
        {
            float4 v0 = *(const float4*)(Arow0 + kb + akq * 4);
            float4 v1 = *(const float4*)(Arow1 + kb + akq * 4);
            As[akq*4+0][ar]    = v0.x; As[akq*4+1][ar]    = v0.y;
            As[akq*4+2][ar]    = v0.z; As[akq*4+3][ar]    = v0.w;
            As[akq*4+0][ar+64] = v1.x; As[akq*4+1][ar+64] = v1.y;
            As[akq*4+2][ar+64] = v1.z; As[akq*4+3][ar+64] = v1.w;
        }
        {
            float4 v = wvalid ? *(const float4*)(Wrow + kb + wkq * 4)
                              : make_float4(0.f, 0.f, 0.f, 0.f);
            Ws[wkq*4+0][wr] = v.x; Ws[wkq*4+1][wr] = v.y;
            Ws[wkq*4+2][wr] = v.z; Ws[wkq*4+3][wr] = v.w;
        }
        __syncthreads();
        #pragma unroll
        for (int kk = 0; kk < BK; kk++) {
            float4 a0 = *(const float4*)&As[kk][ty * 8];
            float4 a1 = *(const float4*)&As[kk][ty * 8 + 4];
            float4 b  = *(const float4*)&Ws[kk][tx * 4];
            float av[8] = {a0.x,a0.y,a0.z,a0.w,a1.x,a1.y,a1.z,a1.w};
            float bv[4] = {b.x,b.y,b.z,b.w};
            #pragma unroll
            for (int i = 0; i < 8; i++)
                #pragma unroll
                for (int j = 0; j < 4; j++)
                    acc[i][j] = fmaf(av[i], bv[j], acc[i][j]);
        }
        __syncthreads();
    }

    const int col = col0 + tx * 4;
    #pragma unroll
    for (int i = 0; i < 8; i++) {
        int row = row0 + ty * 8 + i;
        float* crow = C + (size_t)row * ldc;
        if (col + 4 <= N) {
            float4 o;
            if (EP == EP_SOFTPLUS) {
                float4 bv = *(const float4*)(bias + col);
                o.x = softplusf(acc[i][0] + bv.x);
                o.y = softplusf(acc[i][1] + bv.y);
                o.z = softplusf(acc[i][2] + bv.z);
                o.w = softplusf(acc[i][3] + bv.w);
            } else if (EP == EP_RESID) {
                float4 p = *(const float4*)(crow + col);
                o.x = p.x + acc[i][0]; o.y = p.y + acc[i][1];
                o.z = p.z + acc[i][2]; o.w = p.w + acc[i][3];
            } else {
                o.x = acc[i][0]; o.y = acc[i][1]; o.z = acc[i][2]; o.w = acc[i][3];
            }
            *(float4*)(crow + col) = o;
        } else {
            #pragma unroll
            for (int j = 0; j < 4; j++) {
                int c = col + j;
                if (c < N) {
                    float v = acc[i][j];
                    if (EP == EP_SOFTPLUS) v = softplusf(v + bias[c]);
                    else if (EP == EP_RESID) v += crow[c];
                    crow[c] = v;
                }
            }
        }
    }
}

// ---- bf16 MFMA GEMM: C[M,N] = A[M,K] * B[N,K]^T, fp32 out (m97-structure) ----
typedef __attribute__((ext_vector_type(8))) short bf16x8;
typedef __attribute__((ext_vector_type(4))) float f32x4;

#define GBM 128
#define GBN 128
#define GBK 32

__global__ __launch_bounds__(256)
void gemm_mfma_bf16(const unsigned short* __restrict__ A,   // [M][K] bf16
                    const unsigned short* __restrict__ B,   // [N][K] bf16
                    float* __restrict__ C, int M, int N, int K)
{
    __shared__ __align__(16) unsigned short As[GBM * GBK];
    __shared__ __align__(16) unsigned short Bs[GBN * GBK];

    const int tid  = threadIdx.x;
    const int wave = tid >> 6, lane = tid & 63;
    const int row0 = blockIdx.y * GBM, col0 = blockIdx.x * GBN;
    const int wr = wave >> 1, wc = wave & 1;

    f32x4 acc[4][4] = {};

    const int srow  = lane >> 2;
    const int skoff = (lane & 3) * 8;

    for (int kb = 0; kb < K; kb += GBK) {
        __syncthreads();
        #pragma unroll
        for (int j = 0; j < 2; j++) {
            const int s = wave * 2 + j;
            const unsigned short* ga = A + (size_t)(row0 + s*16 + srow) * K + kb + skoff;
            __builtin_amdgcn_global_load_lds(
                (const __attribute__((address_space(1))) void*)ga,
                (__attribute__((address_space(3))) void*)(As + s * 512), 16, 0, 0);
            const unsigned short* gb = B + (size_t)(col0 + s*16 + srow) * K + kb + skoff;
            __builtin_amdgcn_global_load_lds(
                (const __attribute__((address_space(1))) void*)gb,
                (__attribute__((address_space(3))) void*)(Bs + s * 512), 16, 0, 0);
        }
        __syncthreads();

        const int fr = lane & 15, q = (lane >> 4) * 8;
        bf16x8 af[4], bfr[4];
        #pragma unroll
        for (int m = 0; m < 4; m++)
            af[m] = *(const bf16x8*)&As[(wr*64 + m*16 + fr) * GBK + q];
        #pragma unroll
        for (int n = 0; n < 4; n++)
            bfr[n] = *(const bf16x8*)&Bs[(wc*64 + n*16 + fr) * GBK + q];
        #pragma unroll
        for (int m = 0; m < 4; m++)
            #pragma unroll
            for (int n = 0; n < 4; n++)
                acc[m][n] = __builtin_amdgcn_mfma_f32_16x16x32_bf16(af[m], bfr[n], acc[m][n], 0, 0, 0);
    }

    const int fr = lane & 15, rq = lane >> 4;
    #pragma unroll
    for (int m = 0; m < 4; m++) {
        #pragma unroll
        for (int j = 0; j < 4; j++) {
            int row = row0 + wr*64 + m*16 + rq*4 + j;
            float* crow = C + (size_t)row * N;
            #pragma unroll
            for (int n = 0; n < 4; n++)
                crow[col0 + wc*64 + n*16 + fr] = acc[m][n][j];
        }
    }
}

// ---- causal depthwise conv(4) + bias + silu + cache extraction ----
__global__ __launch_bounds__(256)
void conv_silu_kernel(const float* __restrict__ xz, const float* __restrict__ cw,
                      const float* __restrict__ cb, float* __restrict__ xs,
                      float* __restrict__ cacheOut)
{
    int idx = blockIdx.x * 256 + threadIdx.x;
    int m = idx >> 11;
    int d = idx & (DINNER - 1);
    int l = m & (SEQLEN - 1);
    float4 w4 = *(const float4*)(cw + d * 4);
    float x0 = (l >= 3) ? xz[(size_t)(m - 3) * (2*DINNER) + d] : 0.f;
    float x1 = (l >= 2) ? xz[(size_t)(m - 2) * (2*DINNER) + d] : 0.f;
    float x2 = (l >= 1) ? xz[(size_t)(m - 1) * (2*DINNER) + d] : 0.f;
    float x3 =            xz[(size_t)m       * (2*DINNER) + d];
    float acc = cb[d] + x0*w4.x + x1*w4.y + x2*w4.z + x3*w4.w;
    xs[(size_t)m * DINNER + d] = siluf(acc);
    if (l >= SEQLEN - 3) {
        int j = l - (SEQLEN - 3);
        int b = m >> 10;
        cacheOut[((size_t)b * DINNER + d) * 3 + j] = x3;
    }
}

// ---- selective scan: thread per (b,d,n); software-pipelined time loop ----
// Loop-carried dep is ONLY h = fma(dA,h,dBx) (4 cyc). Everything else (loads,
// exp, reduce, y-write) is independent of h -> chunked register double-buffer
// hides global-load latency under the previous chunk's compute. All array
// indices compile-time (full unroll) so buffers stay in VGPRs (rule #20).
#define SCHUNK 8

__global__ __launch_bounds__(256)
void scan_kernel(const float* __restrict__ delta, const float* __restrict__ dbl,
                 const float* __restrict__ xs, const float* __restrict__ xz,
                 const float* __restrict__ A_log, const float* __restrict__ Dp,
                 float* __restrict__ y, float* __restrict__ hs_out)
{
    const int tid = threadIdx.x;
    const int ch = tid >> 4, n = tid & 15;
    const int g = blockIdx.x * 16 + ch;
    const int b = g >> 11, d = g & (DINNER - 1);
    const float a  = -expf(A_log[(size_t)d * DSTATE + n]);
    const float dp = Dp[d];
    float h = 0.f;
    const size_t mbase = (size_t)b * SEQLEN;

    const float* pDelta = delta + mbase * DINNER + d;
    const float* pXs    = xs    + mbase * DINNER + d;
    const float* pB     = dbl   + mbase * 96 + 64 + n;
    const float* pC     = dbl   + mbase * 96 + 80 + n;
    const float* pZ     = xz    + mbase * (2*DINNER) + DINNER + d;
    float*       pY     = y     + mbase * DINNER + d;

#define LOAD_CHUNK(T0, dl, xv, Bn, Cn, zz)                                   \
    do {                                                                     \
        _Pragma("unroll")                                                    \
        for (int j = 0; j < SCHUNK; j++) {                                   \
            size_t tt = (size_t)(T0) + j;                                    \
            dl[j] = pDelta[tt * DINNER];                                     \
            xv[j] = pXs[tt * DINNER];                                        \
            Bn[j] = pB[tt * 96];                                             \
            Cn[j] = pC[tt * 96];                                             \
        }                                                                    \
        if (n == 0) {                                                        \
            _Pragma("unroll")                                                \
            for (int j = 0; j < SCHUNK; j++)                                 \
                zz[j] = pZ[((size_t)(T0) + j) * (2*DINNER)];                 \
        }                                                                    \
    } while (0)

#define COMPUTE_CHUNK(T0, dl, xv, Bn, Cn, zz)                                \
    do {                                                                     \
        float dA_[SCHUNK], dBx_[SCHUNK], pp_[SCHUNK];                        \
        _Pragma("unroll")                                                    \
        for (int j = 0; j < SCHUNK; j++) {                                   \
            dA_[j]  = expf(dl[j] * a);                                       \
            dBx_[j] = dl[j] * Bn[j] * xv[j];                                 \
        }                                                                    \
        _Pragma("unroll")                                                    \
        for (int j = 0; j < SCHUNK; j++) {                                   \
            h = fmaf(dA_[j], h, dBx_[j]);                                    \
            pp_[j] = h * Cn[j];                                              \
        }                                                                    \
        _Pragma("unroll")                                                    \
        for (int j = 0; j < SCHUNK; j++) {                                   \
            float p = pp_[j];                                                \
            p += __shfl_xor(p, 1, 64); p += __shfl_xor(p, 2, 64);            \
            p += __shfl_xor(p, 4, 64); p += __shfl_xor(p, 8, 64);            \
            if (n == 0)                                                      \
                pY[((size_t)(T0) + j) * DINNER] =                            \
                    (p + dp * xv[j]) * siluf(zz[j]);                         \
        }                                                                    \
    } while (0)

    float dlA[SCHUNK], xvA[SCHUNK], BnA[SCHUNK], CnA[SCHUNK], zzA[SCHUNK];
    float dlB[SCHUNK], xvB[SCHUNK], BnB[SCHUNK], CnB[SCHUNK], zzB[SCHUNK];

    LOAD_CHUNK(0, dlA, xvA, BnA, CnA, zzA);
    for (int t0 = 0; t0 < SEQLEN; t0 += 2*SCHUNK) {
        LOAD_CHUNK(t0 + SCHUNK, dlB, xvB, BnB, CnB, zzB);
        COMPUTE_CHUNK(t0, dlA, xvA, BnA, CnA, zzA);
        if (t0 + 2*SCHUNK < SEQLEN)
            LOAD_CHUNK(t0 + 2*SCHUNK, dlA, xvA, BnA, CnA, zzA);
        COMPUTE_CHUNK(t0 + SCHUNK, dlB, xvB, BnB, CnB, zzB);
    }
#undef LOAD_CHUNK
#undef COMPUTE_CHUNK

    hs_out[((size_t)b * DINNER + d) * DSTATE + n] = h;
}

// ---- driver ----
extern "C" void kernel_launch(void* const* d_in, const int* in_sizes, int n_in,
                              void* d_out, int out_size, void* d_ws, size_t ws_size,
                              hipStream_t stream)
{
    const int*   tokens     = (const int*)  d_in[0];
    const float* embed      = (const float*)d_in[1];
    const float* in_proj_w  = (const float*)d_in[2];
    const float* conv_w     = (const float*)d_in[3];
    const float* conv_b     = (const float*)d_in[4];
    const float* x_proj_w   = (const float*)d_in[5];
    const float* dt_proj_w  = (const float*)d_in[6];
    const float* dt_proj_b  = (const float*)d_in[7];
    const float* A_log      = (const float*)d_in[8];
    const float* D_param    = (const float*)d_in[9];
    const float* out_proj_w = (const float*)d_in[10];
    const float* rms_w      = (const float*)d_in[11];
    const float* norm_f_w   = (const float*)d_in[12];

    float* outp   = (float*)d_out;
    float* logits = outp;
    float* hs     = outp + (size_t)MROWS * VOCABSZ;
    float* caches = hs + (size_t)NLAYERS * BATCH * DINNER * DSTATE;

    float* ws    = (float*)d_ws;
    float* x     = ws;
    float* xn    = x     + (size_t)MROWS * DMODEL;
    float* xz    = xn    + (size_t)MROWS * DMODEL;
    float* xs    = xz    + (size_t)MROWS * 2 * DINNER;
    float* dbl   = xs    + (size_t)MROWS * DINNER;
    float* delta = dbl   + (size_t)MROWS * 96;
    float* yb    = delta + (size_t)MROWS * DINNER;
    unsigned short* xnbf  = (unsigned short*)(yb + (size_t)MROWS * DINNER);
    unsigned short* embbf = xnbf + (size_t)MROWS * DMODEL;

    embed_kernel<<<MROWS, 256, 0, stream>>>(tokens, embed, x);

    f32_to_bf16_kernel<<<(VOCABSZ*DMODEL/4 + 255)/256, 256, 0, stream>>>(
        embed, embbf, VOCABSZ*DMODEL/4);

    for (int l = 0; l < NLAYERS; l++) {
        rmsnorm_kernel<<<MROWS, 256, 0, stream>>>(x, rms_w + (size_t)l * DMODEL, xn);

        gemm_bt<EP_NONE><<<dim3(2*DINNER/BN, MROWS/BM), 256, 0, stream>>>(
            xn, DMODEL, in_proj_w + (size_t)l * 2*DINNER*DMODEL,
            xz, 2*DINNER, nullptr, MROWS, 2*DINNER, DMODEL);

        conv_silu_kernel<<<(MROWS*DINNER)/256, 256, 0, stream>>>(
            xz, conv_w + (size_t)l * DINNER * DCONVK, conv_b + (size_t)l * DINNER,
            xs, caches + (size_t)l * BATCH * DINNER * 3);

        gemm_bt<EP_NONE><<<dim3((96 + BN - 1)/BN, MROWS/BM), 256, 0, stream>>>(
            xs, DINNER, x_proj_w + (size_t)l * 96 * DINNER,
            dbl, 96, nullptr, MROWS, 96, DINNER);

        gemm_bt<EP_SOFTPLUS><<<dim3(DINNER/BN, MROWS/BM), 256, 0, stream>>>(
            dbl, 96, dt_proj_w + (size_t)l * DINNER * DTRANK,
            delta, DINNER, dt_proj_b + (size_t)l * DINNER, MROWS, DINNER, DTRANK);

        scan_kernel<<<(BATCH*DINNER)/16, 256, 0, stream>>>(
            delta, dbl, xs, xz,
            A_log + (size_t)l * DINNER * DSTATE, D_param + (size_t)l * DINNER,
            yb, hs + (size_t)l * BATCH * DINNER * DSTATE);

        gemm_bt<EP_RESID><<<dim3(DMODEL/BN, MROWS/BM), 256, 0, stream>>>(
            yb, DINNER, out_proj_w + (size_t)l * DMODEL * DINNER,
            x, DMODEL, nullptr, MROWS, DMODEL, DINNER);
    }

    rmsnorm_kernel<<<MROWS, 256, 0, stream>>>(x, norm_f_w, xn);

    f32_to_bf16_kernel<<<(MROWS*DMODEL/4 + 255)/256, 256, 0, stream>>>(
        xn, xnbf, MROWS*DMODEL/4);

    gemm_mfma_bf16<<<dim3(VOCABSZ/GBN, MROWS/GBM), 256, 0, stream>>>(
        xnbf, embbf, logits, MROWS, VOCABSZ, DMODEL);
}